// Round 6
// baseline (245.190 us; speedup 1.0000x reference)
//
#include <hip/hip_runtime.h>
#include <hip/hip_bf16.h>
#include <math.h>

#define BB 1024
#define DD 64
#define HH 128

typedef __bf16 bf16x8 __attribute__((ext_vector_type(8)));
typedef float floatx4 __attribute__((ext_vector_type(4)));

__device__ __forceinline__ unsigned short f2bf(float v) {
    union { float f; unsigned u; } a; a.f = v;
    unsigned r = a.u + 0x7fffu + ((a.u >> 16) & 1u);
    return (unsigned short)(r >> 16);
}

// ---------------------------------------------------------------------------
// Prep: c1[i,h] = x_i @ (Wi+Wd) + b1  (fp32, folded into MFMA C-init later)
//       wpack   = [Wab ; Wj-Wd] (K=128) in per-lane bf16 MFMA B-fragment order:
//         wpack[((hh*16 + t4*4 + c)*64 + l)*8 + jj] =
//           c<2 : bf16( Wab[c*32 + (l>>4)*8 + jj][hh*64 + t4*16 + (l&15)] )
//           c>=2: bf16( Wj[k'] - Wd[k'] ), k' = (c-2)*32 + (l>>4)*8 + jj
// Grid 128 x 256. Block = 8 i rows x 32 h-quads; W1 reads are float4.
// ---------------------------------------------------------------------------
__global__ __launch_bounds__(256) void prep_kernel(
    const float* __restrict__ x, const float* __restrict__ W1,
    const float* __restrict__ b1,
    float* __restrict__ c1, unsigned short* __restrict__ wpack)
{
    __shared__ float xs[8][DD];
    const int t = threadIdx.x;
    const int i0 = blockIdx.x * 8;
    xs[t >> 6][t & 63] = x[i0 * DD + t];
    xs[4 + (t >> 6)][t & 63] = x[i0 * DD + 256 + t];
    __syncthreads();

    const int ii = t >> 5;           // 0..7
    const int h4 = t & 31;           // h-quad
    const int h = h4 * 4;
    const int i = i0 + ii;

    float4 a1 = {0.f, 0.f, 0.f, 0.f};
    #pragma unroll 4
    for (int k = 0; k < DD; k++) {
        float4 wi = *(const float4*)(W1 + k * HH + h);
        float4 wd = *(const float4*)(W1 + (2 * DD + k) * HH + h);
        float xv = xs[ii][k];
        a1.x = fmaf(xv, wi.x + wd.x, a1.x);
        a1.y = fmaf(xv, wi.y + wd.y, a1.y);
        a1.z = fmaf(xv, wi.z + wd.z, a1.z);
        a1.w = fmaf(xv, wi.w + wd.w, a1.w);
    }
    float4 b1v = *(const float4*)(b1 + h);
    float4 c1v = {a1.x + b1v.x, a1.y + b1v.y, a1.z + b1v.z, a1.w + b1v.w};
    *(float4*)(c1 + i * HH + h) = c1v;

    if (blockIdx.x < 64) {
        int f = blockIdx.x * 256 + t;          // 0..16383
        int jj = f & 7;
        int l  = (f >> 3) & 63;
        int u  = f >> 9;                       // hh*16 + t4*4 + c
        int c  = u & 3, t4 = (u >> 2) & 3, hh = u >> 4;
        int hcol = hh * 64 + t4 * 16 + (l & 15);
        float val;
        if (c < 2) {
            int k = c * 32 + ((l >> 4) << 3) + jj;
            val = W1[(3 * DD + k) * HH + hcol];                  // Wab
        } else {
            int k = (c - 2) * 32 + ((l >> 4) << 3) + jj;
            val = W1[(DD + k) * HH + hcol] - W1[(2 * DD + k) * HH + hcol]; // Wj-Wd
        }
        wpack[f] = f2bf(val);
    }
}

// ---------------------------------------------------------------------------
// Pair kernel (barrier-free, no LDS):
//   Sp[jh][i][h] = sum_{j in half jh} relu([|x_i-x_j| ; x_j] @ [Wab;Wj-Wd] + c1[i])
// Grid 1024 = 256 i-groups x 2 h-halves x 2 j-halves. Block = 4 waves = 4 i.
// Each wave: 1 i, 64 h, 512 j as 32 tiles of 16 j. xj tiles double-buffered
// in registers (4 dwordx4, prefetched 1 tile ahead); waves fully independent.
// ---------------------------------------------------------------------------
#define LOADT(P0, P1, P2, P3, tile) do {                     \
    const float* rp_ = xrow + ((tile) & 31) * (16 * DD);     \
    P0 = *(const float4*)(rp_);                              \
    P1 = *(const float4*)(rp_ + 4);                          \
    P2 = *(const float4*)(rp_ + 32);                         \
    P3 = *(const float4*)(rp_ + 36);                         \
} while (0)

#define COMPT(A0, A1, A2, A3) do {                                            \
    bf16x8 af0, af1, af2, af3;                                                \
    af0[0]=(__bf16)fabsf(xi[0]-A0.x);  af0[1]=(__bf16)fabsf(xi[1]-A0.y);      \
    af0[2]=(__bf16)fabsf(xi[2]-A0.z);  af0[3]=(__bf16)fabsf(xi[3]-A0.w);      \
    af0[4]=(__bf16)fabsf(xi[4]-A1.x);  af0[5]=(__bf16)fabsf(xi[5]-A1.y);      \
    af0[6]=(__bf16)fabsf(xi[6]-A1.z);  af0[7]=(__bf16)fabsf(xi[7]-A1.w);      \
    af1[0]=(__bf16)fabsf(xi[8]-A2.x);  af1[1]=(__bf16)fabsf(xi[9]-A2.y);      \
    af1[2]=(__bf16)fabsf(xi[10]-A2.z); af1[3]=(__bf16)fabsf(xi[11]-A2.w);     \
    af1[4]=(__bf16)fabsf(xi[12]-A3.x); af1[5]=(__bf16)fabsf(xi[13]-A3.y);     \
    af1[6]=(__bf16)fabsf(xi[14]-A3.z); af1[7]=(__bf16)fabsf(xi[15]-A3.w);     \
    af2[0]=(__bf16)A0.x; af2[1]=(__bf16)A0.y; af2[2]=(__bf16)A0.z;            \
    af2[3]=(__bf16)A0.w; af2[4]=(__bf16)A1.x; af2[5]=(__bf16)A1.y;            \
    af2[6]=(__bf16)A1.z; af2[7]=(__bf16)A1.w;                                 \
    af3[0]=(__bf16)A2.x; af3[1]=(__bf16)A2.y; af3[2]=(__bf16)A2.z;            \
    af3[3]=(__bf16)A2.w; af3[4]=(__bf16)A3.x; af3[5]=(__bf16)A3.y;            \
    af3[6]=(__bf16)A3.z; af3[7]=(__bf16)A3.w;                                 \
    _Pragma("unroll")                                                         \
    for (int t4 = 0; t4 < 4; t4++) {                                          \
        floatx4 acc = {c1r[t4], c1r[t4], c1r[t4], c1r[t4]};                   \
        acc = __builtin_amdgcn_mfma_f32_16x16x32_bf16(af0, wf[t4*4+0], acc, 0,0,0); \
        acc = __builtin_amdgcn_mfma_f32_16x16x32_bf16(af1, wf[t4*4+1], acc, 0,0,0); \
        acc = __builtin_amdgcn_mfma_f32_16x16x32_bf16(af2, wf[t4*4+2], acc, 0,0,0); \
        acc = __builtin_amdgcn_mfma_f32_16x16x32_bf16(af3, wf[t4*4+3], acc, 0,0,0); \
        S[t4] += fmaxf(acc[0], 0.f) + fmaxf(acc[1], 0.f)                      \
               + fmaxf(acc[2], 0.f) + fmaxf(acc[3], 0.f);                     \
    }                                                                         \
} while (0)

__global__ __launch_bounds__(256) void pair_kernel(
    const float* __restrict__ x, const float* __restrict__ c1,
    const unsigned short* __restrict__ wpack, float* __restrict__ Sp)
{
    const int t = threadIdx.x;
    const int wave = t >> 6;
    const int l = t & 63;
    const int quad = l >> 4, lm = l & 15;
    const int bid = blockIdx.x;
    const int ig = bid >> 2;
    const int hh = (bid >> 1) & 1;
    const int jh = bid & 1;
    const int i = ig * 4 + wave;

    // xi slice for this lane's k positions (k = quad*8 + jj, +32)
    float xi[16];
    {
        const float* xg = x + i * DD + quad * 8;
        *(float4*)(xi)      = *(const float4*)(xg);
        *(float4*)(xi + 4)  = *(const float4*)(xg + 4);
        *(float4*)(xi + 8)  = *(const float4*)(xg + 32);
        *(float4*)(xi + 12) = *(const float4*)(xg + 36);
    }
    float c1r[4];
    #pragma unroll
    for (int t4 = 0; t4 < 4; t4++)
        c1r[t4] = c1[i * HH + hh * 64 + t4 * 16 + lm];

    bf16x8 wf[16];
    #pragma unroll
    for (int u = 0; u < 16; u++)
        wf[u] = *(const bf16x8*)(wpack + ((hh * 16 + u) * 64 + l) * 8);

    float S[4] = {0.f, 0.f, 0.f, 0.f};

    // per-lane A-row base: row j = jh*512 + tile*16 + lm, cols quad*8(+32)
    const float* xrow = x + (jh * 512 + lm) * DD + quad * 8;

    float4 A0, A1, A2, A3, B0, B1, B2, B3;
    LOADT(A0, A1, A2, A3, 0);
    LOADT(B0, B1, B2, B3, 1);

    #pragma unroll 1
    for (int tp = 0; tp < 32; tp += 2) {
        COMPT(A0, A1, A2, A3);
        LOADT(A0, A1, A2, A3, tp + 2);
        COMPT(B0, B1, B2, B3);
        LOADT(B0, B1, B2, B3, tp + 3);
    }

    // reduce across the 4 quads (same h = lm+16*t4, different j-rows)
    #pragma unroll
    for (int t4 = 0; t4 < 4; t4++) {
        S[t4] += __shfl_xor(S[t4], 16, 64);
        S[t4] += __shfl_xor(S[t4], 32, 64);
    }
    if (quad == 0) {
        #pragma unroll
        for (int t4 = 0; t4 < 4; t4++)
            Sp[(jh * BB + i) * HH + hh * 64 + t4 * 16 + lm] = S[t4];
    }
}

// ---------------------------------------------------------------------------
// Finish: per row i:  m = (b2 + (mean_j S) @ W2)/tau ; h = relu(m@Wa+ba);
//   y = h + x@Wr + br; out = LayerNorm(y)*gamma+beta.
// Grid 128 x 256. Block = 8 i rows x 32 h-quads; weights read as float4.
// ---------------------------------------------------------------------------
__global__ __launch_bounds__(256) void finish_kernel(
    const float* __restrict__ Sp, const float* __restrict__ W2,
    const float* __restrict__ b2, const float* __restrict__ x,
    const float* __restrict__ Wt, const float* __restrict__ bt,
    const float* __restrict__ Wa, const float* __restrict__ ba,
    const float* __restrict__ Wr, const float* __restrict__ br,
    const float* __restrict__ gamma, const float* __restrict__ beta,
    float* __restrict__ out)
{
    __shared__ float Srow[8][HH];
    __shared__ float mrow[8][HH];
    __shared__ float xrowS[8][DD];
    __shared__ float taus[8];
    const int t = threadIdx.x;
    const int ii = t >> 5;          // 0..7
    const int h4 = t & 31;
    const int h = h4 * 4;
    const int i0 = blockIdx.x * 8;
    const int i = i0 + ii;

    {
        float4 s = {0.f, 0.f, 0.f, 0.f};
        #pragma unroll
        for (int q = 0; q < 2; q++) {
            float4 v = *(const float4*)(Sp + (q * BB + i) * HH + h);
            s.x += v.x; s.y += v.y; s.z += v.z; s.w += v.w;
        }
        const float inv = 1.0f / (float)BB;
        float4 sm = {s.x * inv, s.y * inv, s.z * inv, s.w * inv};
        *(float4*)(&Srow[ii][h]) = sm;
    }
    xrowS[t >> 6][t & 63] = x[i0 * DD + t];
    xrowS[4 + (t >> 6)][t & 63] = x[i0 * DD + 256 + t];

    {
        float p = x[i * DD + h4] * Wt[h4] + x[i * DD + 32 + h4] * Wt[32 + h4];
        #pragma unroll
        for (int off = 16; off; off >>= 1) p += __shfl_xor(p, off, 64);
        if (h4 == 0) {
            float z = p + bt[0];
            float sp = (z > 20.f) ? z : log1pf(expf(z));
            taus[ii] = fmaxf(sp, 0.01f) + 1.0f;
        }
    }
    __syncthreads();

    float4 acc = *(const float4*)(b2 + h);
    #pragma unroll 8
    for (int k = 0; k < HH; k++) {
        float4 w = *(const float4*)(W2 + k * HH + h);
        float sv = Srow[ii][k];
        acc.x = fmaf(sv, w.x, acc.x); acc.y = fmaf(sv, w.y, acc.y);
        acc.z = fmaf(sv, w.z, acc.z); acc.w = fmaf(sv, w.w, acc.w);
    }
    const float itau = 1.0f / taus[ii];
    float4 mv = {acc.x * itau, acc.y * itau, acc.z * itau, acc.w * itau};
    *(float4*)(&mrow[ii][h]) = mv;
    __syncthreads();

    float4 a2 = *(const float4*)(ba + h);
    #pragma unroll 8
    for (int k = 0; k < HH; k++) {
        float4 w = *(const float4*)(Wa + k * HH + h);
        float sv = mrow[ii][k];
        a2.x = fmaf(sv, w.x, a2.x); a2.y = fmaf(sv, w.y, a2.y);
        a2.z = fmaf(sv, w.z, a2.z); a2.w = fmaf(sv, w.w, a2.w);
    }
    float4 brv = *(const float4*)(br + h);
    float4 y = {fmaxf(a2.x, 0.f) + brv.x, fmaxf(a2.y, 0.f) + brv.y,
                fmaxf(a2.z, 0.f) + brv.z, fmaxf(a2.w, 0.f) + brv.w};
    #pragma unroll 8
    for (int d = 0; d < DD; d++) {
        float4 w = *(const float4*)(Wr + d * HH + h);
        float xv = xrowS[ii][d];
        y.x = fmaf(xv, w.x, y.x); y.y = fmaf(xv, w.y, y.y);
        y.z = fmaf(xv, w.z, y.z); y.w = fmaf(xv, w.w, y.w);
    }

    float p = y.x + y.y + y.z + y.w;
    #pragma unroll
    for (int off = 16; off; off >>= 1) p += __shfl_xor(p, off, 64);
    float mu = p * (1.0f / (float)HH);
    float4 dy = {y.x - mu, y.y - mu, y.z - mu, y.w - mu};
    float q = dy.x * dy.x + dy.y * dy.y + dy.z * dy.z + dy.w * dy.w;
    #pragma unroll
    for (int off = 16; off; off >>= 1) q += __shfl_xor(q, off, 64);
    float rs = rsqrtf(q * (1.0f / (float)HH) + 1e-5f);
    float4 gv = *(const float4*)(gamma + h);
    float4 bv = *(const float4*)(beta + h);
    float4 o = {dy.x * rs * gv.x + bv.x, dy.y * rs * gv.y + bv.y,
                dy.z * rs * gv.z + bv.z, dy.w * rs * gv.w + bv.w};
    *(float4*)(out + i * HH + h) = o;
}

// ---------------------------------------------------------------------------
extern "C" void kernel_launch(void* const* d_in, const int* in_sizes, int n_in,
                              void* d_out, int out_size, void* d_ws, size_t ws_size,
                              hipStream_t stream)
{
    const float* x     = (const float*)d_in[0];
    const float* W1    = (const float*)d_in[1];
    const float* b1    = (const float*)d_in[2];
    const float* W2    = (const float*)d_in[3];
    const float* b2    = (const float*)d_in[4];
    const float* Wt    = (const float*)d_in[5];
    const float* bt    = (const float*)d_in[6];
    const float* Wa    = (const float*)d_in[7];
    const float* ba    = (const float*)d_in[8];
    const float* Wr    = (const float*)d_in[9];
    const float* br    = (const float*)d_in[10];
    const float* gamma = (const float*)d_in[11];
    const float* beta  = (const float*)d_in[12];
    float* out = (float*)d_out;

    char* ws = (char*)d_ws;
    float*          c1    = (float*)(ws);                        // 512 KB
    unsigned short* wpack = (unsigned short*)(ws + (512 << 10)); // 32 KB
    float*          Sp    = (float*)(ws + (576 << 10));          // 1 MB

    prep_kernel<<<128, 256, 0, stream>>>(x, W1, b1, c1, wpack);
    pair_kernel<<<1024, 256, 0, stream>>>(x, c1, wpack, Sp);
    finish_kernel<<<128, 256, 0, stream>>>(Sp, W2, b2, x, Wt, bt,
                                           Wa, ba, Wr, br, gamma, beta, out);
}

// Round 8
// 133.744 us; speedup vs baseline: 1.8333x; 1.8333x over previous
//
#include <hip/hip_runtime.h>
#include <hip/hip_bf16.h>
#include <math.h>

#define BB 1024
#define DD 64
#define HH 128

typedef _Float16 half8 __attribute__((ext_vector_type(8)));
typedef __fp16 fp16x2 __attribute__((ext_vector_type(2)));
typedef float floatx4 __attribute__((ext_vector_type(4)));

union H8 { fp16x2 p[4]; half8 v; };

// async global -> LDS, 16B per lane. lds base must be wave-uniform; HW adds lane*16.
__device__ __forceinline__ void async_cp16(const float* g, float* lds_wave_base) {
    __builtin_amdgcn_global_load_lds(
        (const __attribute__((address_space(1))) unsigned int*)g,
        (__attribute__((address_space(3))) unsigned int*)lds_wave_base,
        16, 0, 0);
}

// ---------------------------------------------------------------------------
// Prep: c1[i,h] = x_i @ (Wi+Wd) + b1  (f32)
//       c2P = x_j @ (Wj-Wd) in hh-split MFMA C-fragment order:
//         c2P[(j>>4)*2048 + (h>>6)*1024 + ((h>>4)&3)*256
//             + ((j&15)>>2)*64 + (h&15)*4 + (j&3)]
//       wpack (f16) = Wab in per-lane MFMA B-fragment order, hh-major:
//         wpack[((hh*8 + t4*2 + s)*64 + l)*8 + jj]
//           = f16( Wab[s*32 + (l>>4)*8 + jj][hh*64 + t4*16 + (l&15)] )
// Grid 128 x 256. Block = 8 i rows x 32 h-quads; W1 reads are float4.
// ---------------------------------------------------------------------------
__global__ __launch_bounds__(256) void prep_kernel(
    const float* __restrict__ x, const float* __restrict__ W1,
    const float* __restrict__ b1,
    float* __restrict__ c1, float* __restrict__ c2P,
    _Float16* __restrict__ wpack)
{
    __shared__ float xs[8][DD];
    const int t = threadIdx.x;
    const int i0 = blockIdx.x * 8;
    xs[t >> 6][t & 63] = x[i0 * DD + t];
    xs[4 + (t >> 6)][t & 63] = x[i0 * DD + 256 + t];
    __syncthreads();

    const int ii = t >> 5;           // 0..7
    const int h4 = t & 31;           // h-quad
    const int h = h4 * 4;
    const int i = i0 + ii;

    float4 a1 = {0.f, 0.f, 0.f, 0.f};
    float4 a2 = {0.f, 0.f, 0.f, 0.f};
    #pragma unroll 4
    for (int k = 0; k < DD; k++) {
        float4 wi = *(const float4*)(W1 + k * HH + h);
        float4 wj = *(const float4*)(W1 + (DD + k) * HH + h);
        float4 wd = *(const float4*)(W1 + (2 * DD + k) * HH + h);
        float xv = xs[ii][k];
        a1.x = fmaf(xv, wi.x + wd.x, a1.x);
        a1.y = fmaf(xv, wi.y + wd.y, a1.y);
        a1.z = fmaf(xv, wi.z + wd.z, a1.z);
        a1.w = fmaf(xv, wi.w + wd.w, a1.w);
        a2.x = fmaf(xv, wj.x - wd.x, a2.x);
        a2.y = fmaf(xv, wj.y - wd.y, a2.y);
        a2.z = fmaf(xv, wj.z - wd.z, a2.z);
        a2.w = fmaf(xv, wj.w - wd.w, a2.w);
    }
    float4 b1v = *(const float4*)(b1 + h);
    float4 c1v = {a1.x + b1v.x, a1.y + b1v.y, a1.z + b1v.z, a1.w + b1v.w};
    *(float4*)(c1 + i * HH + h) = c1v;

    // scatter a2 into hh-split fragment order
    const int jl = i & 15;
    float* cb = c2P + (i >> 4) * 2048 + (h >> 6) * 1024 + ((h >> 4) & 3) * 256 + (jl & 3);
    const int p0 = (jl >> 2) * 16 + (h & 15);
    cb[(p0 + 0) * 4] = a2.x;
    cb[(p0 + 1) * 4] = a2.y;
    cb[(p0 + 2) * 4] = a2.z;
    cb[(p0 + 3) * 4] = a2.w;

    if (blockIdx.x < 32) {
        int f = blockIdx.x * 256 + t;        // 0..8191
        int jj = f & 7;
        int l  = (f >> 3) & 63;
        int u  = f >> 9;                     // hh*8 + t4*2 + s
        int s  = u & 1, t4 = (u >> 1) & 3, hh = u >> 3;
        int k  = s * 32 + ((l >> 4) << 3) + jj;
        int hcol = hh * 64 + t4 * 16 + (l & 15);
        wpack[f] = (_Float16)W1[(3 * DD + k) * HH + hcol];
    }
}

// ---------------------------------------------------------------------------
// Pair kernel: Sp[jq][i][hh*64+..] = sum_{j in quarter jq}
//                relu(|x_i-x_j| @ Wab[:,h-half] + c1[i] + c2[j])
// Grid 2048 = 256 ig x 2 hh x 4 jq. Block = 4 waves = 4 i, one h-half.
// Per-wave: 1 i, 64 h (wf = 8 f16 frags = 32 VGPR, acc 16 -> VGPR-resident).
// xs (f32, XOR-swizzled) + c2 half-tile (4 KB) staged async, double-buffered.
// A-operand built in f16 via v_cvt_pkrtz (2 conv/instr, abs folded).
// ---------------------------------------------------------------------------
__global__ __launch_bounds__(256, 4) void pair_kernel(
    const float* __restrict__ x, const float* __restrict__ c1,
    const float* __restrict__ c2P, const _Float16* __restrict__ wpack,
    float* __restrict__ Sp)
{
    __shared__ __align__(16) float xs[2][1024];   // 2 x 4 KB (16 j x 64 k, swizzled)
    __shared__ __align__(16) float c2s[2][1024];  // 2 x 4 KB (hh-half fragment order)

    const int t = threadIdx.x;
    const int wave = t >> 6;
    const int l = t & 63;
    const int quad = l >> 4, lm = l & 15;
    const int bid = blockIdx.x;
    const int ig = bid >> 3;
    const int hh = (bid >> 2) & 1;
    const int jq = bid & 3;
    const int i = ig * 4 + wave;
    const int j0base = jq * 256;
    const int sw = lm & 7;

    // stage tile 0 (async): xs swizzled; c2 half-tile
    async_cp16(x + (j0base + (t >> 4)) * DD + (((t & 15) ^ ((t >> 4) & 7)) << 2),
               &xs[0][0] + wave * 256);
    async_cp16(c2P + (j0base >> 4) * 2048 + hh * 1024 + t * 4,
               &c2s[0][0] + wave * 256);

    // wave-private register data (overlaps staging)
    float xi[16];
    {
        const float* xg = x + i * DD + quad * 8;
        *(float4*)(xi)      = *(const float4*)(xg);
        *(float4*)(xi + 4)  = *(const float4*)(xg + 4);
        *(float4*)(xi + 8)  = *(const float4*)(xg + 32);
        *(float4*)(xi + 12) = *(const float4*)(xg + 36);
    }
    float c1r[4];
    #pragma unroll
    for (int t4 = 0; t4 < 4; t4++)
        c1r[t4] = c1[i * HH + hh * 64 + t4 * 16 + lm];
    half8 wf[8];
    #pragma unroll
    for (int u = 0; u < 8; u++)
        wf[u] = *(const half8*)(wpack + ((hh * 8 + u) * 64 + l) * 8);

    float S[4] = {0.f, 0.f, 0.f, 0.f};

    for (int tile = 0; tile < 16; ++tile) {
        const int cur = tile & 1;
        __syncthreads();   // staged data for 'tile' landed; other buffer free

        if (tile < 15) {   // prefetch next tile (async)
            const int jn = j0base + (tile + 1) * 16;
            async_cp16(x + (jn + (t >> 4)) * DD + (((t & 15) ^ ((t >> 4) & 7)) << 2),
                       &xs[cur ^ 1][0] + wave * 256);
            async_cp16(c2P + (jn >> 4) * 2048 + hh * 1024 + t * 4,
                       &c2s[cur ^ 1][0] + wave * 256);
        }

        // acc init = c2 (fragment-ordered LDS b128) + c1
        floatx4 acc[4];
        #pragma unroll
        for (int t4 = 0; t4 < 4; t4++) {
            float4 c2v = *(const float4*)(&c2s[cur][t4 * 256 + l * 4]);
            acc[t4][0] = c2v.x + c1r[t4];
            acc[t4][1] = c2v.y + c1r[t4];
            acc[t4][2] = c2v.z + c1r[t4];
            acc[t4][3] = c2v.w + c1r[t4];
        }

        // A fragment: row r=lm, chunks quad*2, +1, +8, +9, swizzled by sw=lm&7
        const float* xb = &xs[cur][lm * 64];
        float4 a0 = *(const float4*)(xb + (((quad * 2)     ^ sw) << 2));
        float4 a1 = *(const float4*)(xb + (((quad * 2 + 1) ^ sw) << 2));
        float4 a2 = *(const float4*)(xb + (((quad * 2 + 8) ^ sw) << 2));
        float4 a3 = *(const float4*)(xb + (((quad * 2 + 9) ^ sw) << 2));
        H8 af0, af1;
        af0.p[0] = __builtin_amdgcn_cvt_pkrtz(fabsf(xi[0] - a0.x),  fabsf(xi[1] - a0.y));
        af0.p[1] = __builtin_amdgcn_cvt_pkrtz(fabsf(xi[2] - a0.z),  fabsf(xi[3] - a0.w));
        af0.p[2] = __builtin_amdgcn_cvt_pkrtz(fabsf(xi[4] - a1.x),  fabsf(xi[5] - a1.y));
        af0.p[3] = __builtin_amdgcn_cvt_pkrtz(fabsf(xi[6] - a1.z),  fabsf(xi[7] - a1.w));
        af1.p[0] = __builtin_amdgcn_cvt_pkrtz(fabsf(xi[8] - a2.x),  fabsf(xi[9] - a2.y));
        af1.p[1] = __builtin_amdgcn_cvt_pkrtz(fabsf(xi[10] - a2.z), fabsf(xi[11] - a2.w));
        af1.p[2] = __builtin_amdgcn_cvt_pkrtz(fabsf(xi[12] - a3.x), fabsf(xi[13] - a3.y));
        af1.p[3] = __builtin_amdgcn_cvt_pkrtz(fabsf(xi[14] - a3.z), fabsf(xi[15] - a3.w));

        #pragma unroll
        for (int t4 = 0; t4 < 4; t4++) {
            acc[t4] = __builtin_amdgcn_mfma_f32_16x16x32_f16(af0.v, wf[t4 * 2 + 0], acc[t4], 0, 0, 0);
            acc[t4] = __builtin_amdgcn_mfma_f32_16x16x32_f16(af1.v, wf[t4 * 2 + 1], acc[t4], 0, 0, 0);
        }
        #pragma unroll
        for (int t4 = 0; t4 < 4; t4++) {
            S[t4] += fmaxf(acc[t4][0], 0.f);
            S[t4] += fmaxf(acc[t4][1], 0.f);
            S[t4] += fmaxf(acc[t4][2], 0.f);
            S[t4] += fmaxf(acc[t4][3], 0.f);
        }
    }

    // reduce across the 4 quads (same h = lm+16*t4, different j-rows)
    #pragma unroll
    for (int t4 = 0; t4 < 4; t4++) {
        S[t4] += __shfl_xor(S[t4], 16, 64);
        S[t4] += __shfl_xor(S[t4], 32, 64);
    }
    if (quad == 0) {
        #pragma unroll
        for (int t4 = 0; t4 < 4; t4++)
            Sp[(jq * BB + i) * HH + hh * 64 + t4 * 16 + lm] = S[t4];
    }
}

// ---------------------------------------------------------------------------
// Finish: per row i:  m = (b2 + (mean_j S) @ W2)/tau ; h = relu(m@Wa+ba);
//   y = h + x@Wr + br; out = LayerNorm(y)*gamma+beta.
// Grid 128 x 256. Block = 8 i rows x 32 h-quads; weights read as float4.
// ---------------------------------------------------------------------------
__global__ __launch_bounds__(256) void finish_kernel(
    const float* __restrict__ Sp, const float* __restrict__ W2,
    const float* __restrict__ b2, const float* __restrict__ x,
    const float* __restrict__ Wt, const float* __restrict__ bt,
    const float* __restrict__ Wa, const float* __restrict__ ba,
    const float* __restrict__ Wr, const float* __restrict__ br,
    const float* __restrict__ gamma, const float* __restrict__ beta,
    float* __restrict__ out)
{
    __shared__ float Srow[8][HH];
    __shared__ float mrow[8][HH];
    __shared__ float xrowS[8][DD];
    __shared__ float taus[8];
    const int t = threadIdx.x;
    const int ii = t >> 5;          // 0..7
    const int h4 = t & 31;
    const int h = h4 * 4;
    const int i0 = blockIdx.x * 8;
    const int i = i0 + ii;

    {
        float4 s = {0.f, 0.f, 0.f, 0.f};
        #pragma unroll
        for (int q = 0; q < 4; q++) {
            float4 v = *(const float4*)(Sp + (q * BB + i) * HH + h);
            s.x += v.x; s.y += v.y; s.z += v.z; s.w += v.w;
        }
        const float inv = 1.0f / (float)BB;
        float4 sm = {s.x * inv, s.y * inv, s.z * inv, s.w * inv};
        *(float4*)(&Srow[ii][h]) = sm;
    }
    xrowS[t >> 6][t & 63] = x[i0 * DD + t];
    xrowS[4 + (t >> 6)][t & 63] = x[i0 * DD + 256 + t];

    {
        float p = x[i * DD + h4] * Wt[h4] + x[i * DD + 32 + h4] * Wt[32 + h4];
        #pragma unroll
        for (int off = 16; off; off >>= 1) p += __shfl_xor(p, off, 64);
        if (h4 == 0) {
            float z = p + bt[0];
            float sp = (z > 20.f) ? z : log1pf(expf(z));
            taus[ii] = fmaxf(sp, 0.01f) + 1.0f;
        }
    }
    __syncthreads();

    float4 acc = *(const float4*)(b2 + h);
    #pragma unroll 8
    for (int k = 0; k < HH; k++) {
        float4 w = *(const float4*)(W2 + k * HH + h);
        float sv = Srow[ii][k];
        acc.x = fmaf(sv, w.x, acc.x); acc.y = fmaf(sv, w.y, acc.y);
        acc.z = fmaf(sv, w.z, acc.z); acc.w = fmaf(sv, w.w, acc.w);
    }
    const float itau = 1.0f / taus[ii];
    float4 mv = {acc.x * itau, acc.y * itau, acc.z * itau, acc.w * itau};
    *(float4*)(&mrow[ii][h]) = mv;
    __syncthreads();

    float4 a2 = *(const float4*)(ba + h);
    #pragma unroll 8
    for (int k = 0; k < HH; k++) {
        float4 w = *(const float4*)(Wa + k * HH + h);
        float sv = mrow[ii][k];
        a2.x = fmaf(sv, w.x, a2.x); a2.y = fmaf(sv, w.y, a2.y);
        a2.z = fmaf(sv, w.z, a2.z); a2.w = fmaf(sv, w.w, a2.w);
    }
    float4 brv = *(const float4*)(br + h);
    float4 y = {fmaxf(a2.x, 0.f) + brv.x, fmaxf(a2.y, 0.f) + brv.y,
                fmaxf(a2.z, 0.f) + brv.z, fmaxf(a2.w, 0.f) + brv.w};
    #pragma unroll 8
    for (int d = 0; d < DD; d++) {
        float4 w = *(const float4*)(Wr + d * HH + h);
        float xv = xrowS[ii][d];
        y.x = fmaf(xv, w.x, y.x); y.y = fmaf(xv, w.y, y.y);
        y.z = fmaf(xv, w.z, y.z); y.w = fmaf(xv, w.w, y.w);
    }

    float p = y.x + y.y + y.z + y.w;
    #pragma unroll
    for (int off = 16; off; off >>= 1) p += __shfl_xor(p, off, 64);
    float mu = p * (1.0f / (float)HH);
    float4 dy = {y.x - mu, y.y - mu, y.z - mu, y.w - mu};
    float q = dy.x * dy.x + dy.y * dy.y + dy.z * dy.z + dy.w * dy.w;
    #pragma unroll
    for (int off = 16; off; off >>= 1) q += __shfl_xor(q, off, 64);
    float rs = rsqrtf(q * (1.0f / (float)HH) + 1e-5f);
    float4 gv = *(const float4*)(gamma + h);
    float4 bv = *(const float4*)(beta + h);
    float4 o = {dy.x * rs * gv.x + bv.x, dy.y * rs * gv.y + bv.y,
                dy.z * rs * gv.z + bv.z, dy.w * rs * gv.w + bv.w};
    *(float4*)(out + i * HH + h) = o;
}

// ---------------------------------------------------------------------------
extern "C" void kernel_launch(void* const* d_in, const int* in_sizes, int n_in,
                              void* d_out, int out_size, void* d_ws, size_t ws_size,
                              hipStream_t stream)
{
    const float* x     = (const float*)d_in[0];
    const float* W1    = (const float*)d_in[1];
    const float* b1    = (const float*)d_in[2];
    const float* W2    = (const float*)d_in[3];
    const float* b2    = (const float*)d_in[4];
    const float* Wt    = (const float*)d_in[5];
    const float* bt    = (const float*)d_in[6];
    const float* Wa    = (const float*)d_in[7];
    const float* ba    = (const float*)d_in[8];
    const float* Wr    = (const float*)d_in[9];
    const float* br    = (const float*)d_in[10];
    const float* gamma = (const float*)d_in[11];
    const float* beta  = (const float*)d_in[12];
    float* out = (float*)d_out;

    char* ws = (char*)d_ws;
    float*     c1    = (float*)(ws);                         // 512 KB
    float*     c2P   = (float*)(ws + (512 << 10));           // 512 KB
    _Float16*  wpack = (_Float16*)(ws + (1024 << 10));       // 16 KB
    float*     Sp    = (float*)(ws + (1056 << 10));          // 2 MB

    prep_kernel<<<128, 256, 0, stream>>>(x, W1, b1, c1, c2P, wpack);
    pair_kernel<<<2048, 256, 0, stream>>>(x, c1, c2P, wpack, Sp);
    finish_kernel<<<128, 256, 0, stream>>>(Sp, W2, b2, x, Wt, bt,
                                           Wa, ba, Wr, br, gamma, beta, out);
}